// Round 7
// baseline (185.918 us; speedup 1.0000x reference)
//
#include <hip/hip_runtime.h>
#include <hip/hip_bf16.h>

// Per (b,c) slice: S = (Q K^T)*di ; A = softmax_rows(S) ; out[i,j] = sum_k A[j,k] V[i,k]
// j-tile 64 (4 blocks/slice, XCD-grouped), 8 waves, all fp16 MFMA 16x16x32.
// mm1: waves = 4 j-groups x 2 k-halves (k-split halves LDS broadcast);
//      K fp16 2-deep prefetch double-buffer. Cross-wave softmax via 1KB partials.
// mm2: 16i x 32j wave tiles, V single-buffered 64-row chunks (aliases Kbuf).
// Raw s_barrier + lgkmcnt(0) only -> global prefetches never drained.
// LDS ~65KB -> 2 blocks/CU (16 waves/CU).

typedef __attribute__((ext_vector_type(8))) _Float16 f16x8;
typedef __attribute__((ext_vector_type(4))) float f32x4;

#define BARRIER() asm volatile("s_waitcnt lgkmcnt(0)\n\ts_barrier" ::: "memory")

__device__ __forceinline__ f32x4 mfma16h(f16x8 a, f16x8 b, f32x4 c) {
  return __builtin_amdgcn_mfma_f32_16x16x32_f16(a, b, c, 0, 0, 0);
}
__device__ __forceinline__ f16x8 cvt8(f32x4 a, f32x4 b) {
  f16x8 r;
  r[0] = (_Float16)a[0]; r[1] = (_Float16)a[1];
  r[2] = (_Float16)a[2]; r[3] = (_Float16)a[3];
  r[4] = (_Float16)b[0]; r[5] = (_Float16)b[1];
  r[6] = (_Float16)b[2]; r[7] = (_Float16)b[3];
  return r;
}
// 512B-row-stride fp16 tiles: XOR 4 row bits into the 16B-slot index
__device__ __forceinline__ int swz(int row, int byteCol) {
  return row * 512 + (byteCol ^ ((row & 15) << 4));
}

__global__ __launch_bounds__(512, 4) void attn_fused7(
    const float* __restrict__ Q, const float* __restrict__ K,
    const float* __restrict__ V, const float* __restrict__ di,
    float* __restrict__ out) {
  __shared__ short Kbuf[2][32 * 256];  // fp16 K chunks (2x16KB); alias: Vlds
  __shared__ short Abuf[64 * 256];     // fp16 attn weights (32KB), swizzled
  __shared__ float pmps[64 * 4];       // per row: 2 x (max, sum) (1KB)
  short* Vlds = &Kbuf[0][0];           // [64 i][256 k] fp16 = 32KB (alias)

  const int t = threadIdx.x;
  const int lane = t & 63;
  const int wv = t >> 6;     // 0..7
  const int l15 = lane & 15;
  const int l4 = (lane >> 4) & 3;

  // 4 sibling blocks of one slice share bid%8 -> same XCD L2
  const int bid = blockIdx.x;
  const int bc = (bid >> 5) * 8 + (bid & 7);  // slice 0..511
  const int j0 = ((bid >> 3) & 3) * 64;       // j-tile origin

  const float dival = di[0];
  const size_t base = (size_t)bc << 16;
  const float* Qs = Q + base;
  const float* Ks = K + base;
  const float* Vs = V + base;
  float* Os = out + base;

  const int jt = wv >> 1;  // j-group (16 rows)
  const int kt = wv & 1;   // k-half of each 32-row K chunk

  // K staging coords: thread loads 16 consecutive floats of a 32x256 chunk
  const int sr = t >> 4;
  const int sc = (t & 15) << 4;

  f32x4 ka0, ka1, ka2, ka3, kb0, kb1, kb2, kb3;  // 2-deep K prefetch
  {
    const float* p = Ks + sr * 256 + sc;
    ka0 = *(const f32x4*)p;
    ka1 = *(const f32x4*)(p + 4);
    ka2 = *(const f32x4*)(p + 8);
    ka3 = *(const f32x4*)(p + 12);
    const float* q = p + 8192;
    kb0 = *(const f32x4*)q;
    kb1 = *(const f32x4*)(q + 4);
    kb2 = *(const f32x4*)(q + 8);
    kb3 = *(const f32x4*)(q + 12);
  }
  f16x8 qh[8];  // wave's 16 Q rows (A-op layout)
  {
    const float* qrow = Qs + (size_t)(j0 + 16 * jt + l15) * 256 + 8 * l4;
#pragma unroll
    for (int s = 0; s < 8; ++s)
      qh[s] = cvt8(*(const f32x4*)(qrow + 32 * s),
                   *(const f32x4*)(qrow + 32 * s + 4));
  }

  f32x4 acc[8];  // S rows j = 16jt+4l4+r ; cols k = 32ch + 16kt + l15
#pragma unroll
  for (int i = 0; i < 8; ++i) acc[i] = (f32x4){0.f, 0.f, 0.f, 0.f};

  // ---- matmul 1: write LDS, issue ch+2, barrier, MFMA (k-half only) ----
#pragma unroll
  for (int ch = 0; ch < 8; ++ch) {
    short* kb = Kbuf[ch & 1];
    if ((ch & 1) == 0) {
      *(f16x8*)((char*)kb + swz(sr, sc * 2)) = cvt8(ka0, ka1);
      *(f16x8*)((char*)kb + swz(sr, sc * 2 + 16)) = cvt8(ka2, ka3);
      if (ch < 6) {
        const float* p = Ks + (ch + 2) * 8192 + sr * 256 + sc;
        ka0 = *(const f32x4*)p;
        ka1 = *(const f32x4*)(p + 4);
        ka2 = *(const f32x4*)(p + 8);
        ka3 = *(const f32x4*)(p + 12);
      }
    } else {
      *(f16x8*)((char*)kb + swz(sr, sc * 2)) = cvt8(kb0, kb1);
      *(f16x8*)((char*)kb + swz(sr, sc * 2 + 16)) = cvt8(kb2, kb3);
      if (ch < 6) {
        const float* p = Ks + (ch + 2) * 8192 + sr * 256 + sc;
        kb0 = *(const f32x4*)p;
        kb1 = *(const f32x4*)(p + 4);
        kb2 = *(const f32x4*)(p + 8);
        kb3 = *(const f32x4*)(p + 12);
      }
    }
    BARRIER();  // writes visible; prior reads done; vmem stays in flight
    __builtin_amdgcn_s_setprio(1);
    const int kr = 16 * kt + l15;
    f32x4 a = acc[ch];
#pragma unroll
    for (int s = 0; s < 8; ++s) {
      f16x8 bh = *(const f16x8*)((const char*)kb + swz(kr, 64 * s + 16 * l4));
      a = mfma16h(qh[s], bh, a);
    }
    acc[ch] = a;
    __builtin_amdgcn_s_setprio(0);
  }

  // ---- V chunk 0 prefetch (flies under softmax): rows 0..63 ----
  const int vr = t >> 3;        // local i-row 0..63
  const int vc = (t & 7) << 5;  // float col, 32 per thread
  f32x4 va[8], vb[8];
  {
    const float* p = Vs + (size_t)vr * 256 + vc;
#pragma unroll
    for (int e = 0; e < 8; ++e) va[e] = *(const f32x4*)(p + 4 * e);
  }

  // ---- softmax: wave-half local (128 cols) + cross-wave combine ----
  float mx[4] = {-1e30f, -1e30f, -1e30f, -1e30f};
#pragma unroll
  for (int ch = 0; ch < 8; ++ch)
#pragma unroll
    for (int r = 0; r < 4; ++r) {
      acc[ch][r] *= dival;
      mx[r] = fmaxf(mx[r], acc[ch][r]);
    }
#pragma unroll
  for (int o = 1; o <= 8; o <<= 1)
#pragma unroll
    for (int r = 0; r < 4; ++r) mx[r] = fmaxf(mx[r], __shfl_xor(mx[r], o));
  float sm[4] = {0.f, 0.f, 0.f, 0.f};
#pragma unroll
  for (int ch = 0; ch < 8; ++ch)
#pragma unroll
    for (int r = 0; r < 4; ++r) {
      acc[ch][r] = __expf(acc[ch][r] - mx[r]);
      sm[r] += acc[ch][r];
    }
#pragma unroll
  for (int o = 1; o <= 8; o <<= 1)
#pragma unroll
    for (int r = 0; r < 4; ++r) sm[r] += __shfl_xor(sm[r], o);
  if (l15 == 0) {
#pragma unroll
    for (int r = 0; r < 4; ++r) {
      const int row = 16 * jt + 4 * l4 + r;
      pmps[row * 4 + 2 * kt] = mx[r];
      pmps[row * 4 + 2 * kt + 1] = sm[r];
    }
  }
  BARRIER();  // partials visible
#pragma unroll
  for (int r = 0; r < 4; ++r) {
    const int row = 16 * jt + 4 * l4 + r;
    f32x4 p = *(const f32x4*)&pmps[row * 4];
    const float mg = fmaxf(p[0], p[2]);
    const float Sg = p[1] * __expf(p[0] - mg) + p[3] * __expf(p[2] - mg);
    const float al = __expf(mx[r] - mg) / Sg;
#pragma unroll
    for (int ch = 0; ch < 8; ++ch) {
      const int col = 32 * ch + 16 * kt + l15;
      *(_Float16*)((char*)Abuf + swz(row, 2 * col)) =
          (_Float16)(acc[ch][r] * al);
    }
  }
  BARRIER();  // A visible; all mm1 K-LDS reads done (Vlds alias safe)

  // ---- matmul 2: 4 chunks of 64 i-rows; wave tile 16i x 32j ----
  const int iq = wv >> 1;  // i 16-group within chunk
  const int jh = wv & 1;   // j 32-group
#pragma unroll
  for (int ci = 0; ci < 4; ++ci) {
    if ((ci & 1) == 0) {
#pragma unroll
      for (int e = 0; e < 4; ++e)
        *(f16x8*)((char*)Vlds + swz(vr, vc * 2 + 16 * e)) =
            cvt8(va[2 * e], va[2 * e + 1]);
      if (ci < 3) {
        const float* p = Vs + (size_t)((ci + 1) * 64 + vr) * 256 + vc;
#pragma unroll
        for (int e = 0; e < 8; ++e) vb[e] = *(const f32x4*)(p + 4 * e);
      }
    } else {
#pragma unroll
      for (int e = 0; e < 4; ++e)
        *(f16x8*)((char*)Vlds + swz(vr, vc * 2 + 16 * e)) =
            cvt8(vb[2 * e], vb[2 * e + 1]);
      if (ci < 3) {
        const float* p = Vs + (size_t)((ci + 1) * 64 + vr) * 256 + vc;
#pragma unroll
        for (int e = 0; e < 8; ++e) va[e] = *(const f32x4*)(p + 4 * e);
      }
    }
    BARRIER();  // V chunk visible
    __builtin_amdgcn_s_setprio(1);
    f32x4 o0 = {0.f, 0.f, 0.f, 0.f}, o1 = {0.f, 0.f, 0.f, 0.f};
#pragma unroll
    for (int ks = 0; ks < 8; ++ks) {
      f16x8 vfrag = *(const f16x8*)((const char*)Vlds +
                                    swz(16 * iq + l15, 64 * ks + 16 * l4));
      f16x8 ab0 = *(const f16x8*)((const char*)Abuf +
                                  swz(32 * jh + l15, 64 * ks + 16 * l4));
      f16x8 ab1 = *(const f16x8*)((const char*)Abuf +
                                  swz(32 * jh + 16 + l15, 64 * ks + 16 * l4));
      o0 = mfma16h(vfrag, ab0, o0);
      o1 = mfma16h(vfrag, ab1, o1);
    }
    __builtin_amdgcn_s_setprio(0);
    // store: D col=l15, row=4*l4+r
    const int rbase = 64 * ci + 16 * iq + 4 * l4;
    const int col = j0 + 32 * jh + l15;
#pragma unroll
    for (int r = 0; r < 4; ++r) {
      Os[(size_t)(rbase + r) * 256 + col] = o0[r];
      Os[(size_t)(rbase + r) * 256 + col + 16] = o1[r];
    }
    BARRIER();  // V reads done before next chunk's write
  }
}

extern "C" void kernel_launch(void* const* d_in, const int* in_sizes, int n_in,
                              void* d_out, int out_size, void* d_ws,
                              size_t ws_size, hipStream_t stream) {
  const float* Q = (const float*)d_in[0];
  const float* K = (const float*)d_in[1];
  const float* V = (const float*)d_in[2];
  const float* di = (const float*)d_in[3];
  float* out = (float*)d_out;
  const int BC = in_sizes[0] / (256 * 256);  // 512 slices
  hipLaunchKernelGGL(attn_fused7, dim3(BC * 4), dim3(512), 0, stream, Q, K, V,
                     di, out);
}

// Round 9
// 142.119 us; speedup vs baseline: 1.3082x; 1.3082x over previous
//
#include <hip/hip_runtime.h>
#include <hip/hip_bf16.h>

// Per (b,c) slice: S = (Q K^T)*di ; A = softmax_rows(S) ; out[i,j] = sum_k A[j,k] V[i,k]
// FLASH STRUCTURE: fused k-chunk loop, P never materialized in LDS.
//   - block = 1 slice x 128 i-rows (2 blocks/slice, XCD-paired); 8 waves.
//   - wave = j-group of 32 (j = 32*wv + l31), out-acc 128i x 32j in regs.
//   - per chunk (64 k): stage K(64x256) + V(128x64) fp16 dbuf -> 1 barrier ->
//     S^T = mfma32(K,Q) (col=j=l31!) -> in-lane online softmax (+1 shfl) ->
//     cvt_pkrtz pack + shfl_xor(32) half-exchange -> P frags in regs ->
//     mm2 partial mfma32(V, P). 4 barriers total per kernel.
//   - epilogue: out = acc / l.

typedef __attribute__((ext_vector_type(8))) _Float16 f16x8;
typedef __attribute__((ext_vector_type(2))) __fp16 fp16v2;
typedef __attribute__((ext_vector_type(4))) float f32x4;
typedef __attribute__((ext_vector_type(16))) float f32x16;
typedef __attribute__((ext_vector_type(4))) unsigned u32x4;

#define BARRIER() asm volatile("s_waitcnt lgkmcnt(0)\n\ts_barrier" ::: "memory")

__device__ __forceinline__ f32x16 mfma32h(f16x8 a, f16x8 b, f32x16 c) {
  return __builtin_amdgcn_mfma_f32_32x32x16_f16(a, b, c, 0, 0, 0);
}
__device__ __forceinline__ f16x8 cvt8(f32x4 a, f32x4 b) {
  f16x8 r;
  r[0] = (_Float16)a[0]; r[1] = (_Float16)a[1];
  r[2] = (_Float16)a[2]; r[3] = (_Float16)a[3];
  r[4] = (_Float16)b[0]; r[5] = (_Float16)b[1];
  r[6] = (_Float16)b[2]; r[7] = (_Float16)b[3];
  return r;
}
__device__ __forceinline__ f16x8 cvt8s(f32x4 a, f32x4 b, float s) {
  f16x8 r;
  r[0] = (_Float16)(a[0] * s); r[1] = (_Float16)(a[1] * s);
  r[2] = (_Float16)(a[2] * s); r[3] = (_Float16)(a[3] * s);
  r[4] = (_Float16)(b[0] * s); r[5] = (_Float16)(b[1] * s);
  r[6] = (_Float16)(b[2] * s); r[7] = (_Float16)(b[3] * s);
  return r;
}
__device__ __forceinline__ unsigned pk2(float a, float b) {
  fp16v2 h = __builtin_amdgcn_cvt_pkrtz(a, b);
  return __builtin_bit_cast(unsigned, h);
}
// K tile [64][256] fp16 (512B row stride): XOR 4 row bits into 16B-slot idx
__device__ __forceinline__ int swzK(int row, int byteCol) {
  return row * 512 + (byteCol ^ ((row & 15) << 4));
}
// V tile [128][64] fp16 (128B row stride): 3 row bits
__device__ __forceinline__ int swzV(int row, int byteCol) {
  return row * 128 + (byteCol ^ ((row & 7) << 4));
}

__global__ __launch_bounds__(512, 1) void attn_flash(
    const float* __restrict__ Q, const float* __restrict__ K,
    const float* __restrict__ V, const float* __restrict__ di,
    float* __restrict__ out) {
  __shared__ short Klds[2][64 * 256];  // 2 x 32KB fp16, swizzled
  __shared__ short Vlds[2][128 * 64];  // 2 x 16KB fp16, swizzled

  const int t = threadIdx.x;
  const int lane = t & 63;
  const int wv = t >> 6;     // 0..7 = j-group
  const int l31 = lane & 31;
  const int h5 = lane >> 5;  // 0..1

  // 2 sibling blocks (i-halves) of one slice share bid%8 -> same XCD L2
  const int bid = blockIdx.x;
  const int bc = (bid >> 4) * 8 + (bid & 7);  // slice 0..511
  const int i0 = ((bid >> 3) & 1) << 7;       // i-half origin: 0 or 128

  const float dival = di[0];
  const size_t base = (size_t)bc << 16;
  const float* Qs = Q + base;
  const float* Ks = K + base;
  const float* Vs = V + base;
  float* Os = out + base;

  // staging coords
  const int kr_r = t >> 3, kr_c = (t & 7) << 5;  // K: 32 floats/thread
  const int vr_r = t >> 2, vr_c = (t & 3) << 4;  // V: 16 floats/thread

  // ---- prologue: issue K,V chunk-0 loads ----
  f32x4 kp[8], vp[4];
  {
    const float* p = Ks + kr_r * 256 + kr_c;
#pragma unroll
    for (int e = 0; e < 8; ++e) kp[e] = *(const f32x4*)(p + 4 * e);
    const float* v = Vs + (size_t)(i0 + vr_r) * 256 + vr_c;
#pragma unroll
    for (int e = 0; e < 4; ++e) vp[e] = *(const f32x4*)(v + 4 * e);
  }
  // Q as B-operand fragments (col = j = l31), pre-scaled by di
  f16x8 qb[16];
  {
    const float* qrow = Qs + (size_t)(32 * wv + l31) * 256 + 8 * h5;
#pragma unroll
    for (int kk = 0; kk < 16; ++kk)
      qb[kk] = cvt8s(*(const f32x4*)(qrow + 16 * kk),
                     *(const f32x4*)(qrow + 16 * kk + 4), dival);
  }

  f32x16 oa0 = {}, oa1 = {}, oa2 = {}, oa3 = {};  // out: 4 i-blocks x 32 j
  float m = -1e30f, l = 0.f;

#pragma unroll
  for (int ch = 0; ch < 4; ++ch) {
    char* kb = (char*)Klds[ch & 1];
    char* vb = (char*)Vlds[ch & 1];
    // ---- stage prefetched chunk -> LDS (fp16, swizzled) ----
#pragma unroll
    for (int e = 0; e < 4; ++e)
      *(f16x8*)(kb + swzK(kr_r, 2 * kr_c + 16 * e)) =
          cvt8(kp[2 * e], kp[2 * e + 1]);
#pragma unroll
    for (int e = 0; e < 2; ++e)
      *(f16x8*)(vb + swzV(vr_r, 2 * vr_c + 16 * e)) =
          cvt8(vp[2 * e], vp[2 * e + 1]);
    BARRIER();  // the ONLY barrier per chunk (dbuf)
    if (ch < 3) {  // issue next-chunk loads; fly under this chunk's compute
      const float* p = Ks + (ch + 1) * 16384 + kr_r * 256 + kr_c;
#pragma unroll
      for (int e = 0; e < 8; ++e) kp[e] = *(const f32x4*)(p + 4 * e);
      const float* v = Vs + (size_t)(i0 + vr_r) * 256 + (ch + 1) * 64 + vr_c;
#pragma unroll
      for (int e = 0; e < 4; ++e) vp[e] = *(const f32x4*)(v + 4 * e);
    }
    // ---- mm1: S^T blocks (km=0,1): D[k_local, j=l31] ----
    f32x16 s0 = {}, s1 = {};
    __builtin_amdgcn_s_setprio(1);
#pragma unroll
    for (int kk = 0; kk < 16; ++kk) {
      f16x8 ka = *(const f16x8*)(kb + swzK(l31, 32 * kk + 16 * h5));
      f16x8 kc = *(const f16x8*)(kb + swzK(32 + l31, 32 * kk + 16 * h5));
      s0 = mfma32h(ka, qb[kk], s0);
      s1 = mfma32h(kc, qb[kk], s1);
    }
    __builtin_amdgcn_s_setprio(0);
    // ---- online softmax (lane owns j = 32wv+l31; partner lane = xor 32) ----
    float cm = -1e30f;
#pragma unroll
    for (int r = 0; r < 16; ++r) cm = fmaxf(cm, fmaxf(s0[r], s1[r]));
    cm = fmaxf(cm, __shfl_xor(cm, 32));
    const float mn = fmaxf(m, cm);
    const float fac = __expf(m - mn);
    float ps = 0.f;
#pragma unroll
    for (int r = 0; r < 16; ++r) {
      s0[r] = __expf(s0[r] - mn);
      s1[r] = __expf(s1[r] - mn);
      ps += s0[r] + s1[r];
    }
    ps += __shfl_xor(ps, 32);
    l = l * fac + ps;
    m = mn;
    oa0 *= fac; oa1 *= fac; oa2 *= fac; oa3 *= fac;
    // ---- pack P -> words W[q][p]; lane holds k = 8q + 4h5 + {0..3} ----
    unsigned W[8][2];
#pragma unroll
    for (int rq = 0; rq < 4; ++rq) {
      W[rq][0] = pk2(s0[4 * rq + 0], s0[4 * rq + 1]);
      W[rq][1] = pk2(s0[4 * rq + 2], s0[4 * rq + 3]);
      W[4 + rq][0] = pk2(s1[4 * rq + 0], s1[4 * rq + 1]);
      W[4 + rq][1] = pk2(s1[4 * rq + 2], s1[4 * rq + 3]);
    }
    // ---- mm2: per kk assemble P frag (half-exchange) + 4 i-block MFMAs ----
    __builtin_amdgcn_s_setprio(1);
#pragma unroll
    for (int kk = 0; kk < 4; ++kk) {
      // own contribution q=2kk+h5; send q=2kk+(1-h5); recv = partner's own-q
      unsigned o0 = h5 ? W[2 * kk + 1][0] : W[2 * kk][0];
      unsigned o1 = h5 ? W[2 * kk + 1][1] : W[2 * kk][1];
      unsigned sd0 = h5 ? W[2 * kk][0] : W[2 * kk + 1][0];
      unsigned sd1 = h5 ? W[2 * kk][1] : W[2 * kk + 1][1];
      unsigned r0 = __shfl_xor(sd0, 32);
      unsigned r1 = __shfl_xor(sd1, 32);
      u32x4 u;
      u[0] = h5 ? r0 : o0;
      u[1] = h5 ? r1 : o1;
      u[2] = h5 ? o0 : r0;
      u[3] = h5 ? o1 : r1;
      f16x8 pf = __builtin_bit_cast(f16x8, u);
      f16x8 v0 = *(const f16x8*)(vb + swzV(l31, 32 * kk + 16 * h5));
      f16x8 v1 = *(const f16x8*)(vb + swzV(32 + l31, 32 * kk + 16 * h5));
      f16x8 v2 = *(const f16x8*)(vb + swzV(64 + l31, 32 * kk + 16 * h5));
      f16x8 v3 = *(const f16x8*)(vb + swzV(96 + l31, 32 * kk + 16 * h5));
      oa0 = mfma32h(v0, pf, oa0);
      oa1 = mfma32h(v1, pf, oa1);
      oa2 = mfma32h(v2, pf, oa2);
      oa3 = mfma32h(v3, pf, oa3);
    }
    __builtin_amdgcn_s_setprio(0);
  }

  // ---- epilogue: normalize by l, store ----
  const float inv = 1.0f / l;
  const int jcol = 32 * wv + l31;
#pragma unroll
  for (int r = 0; r < 16; ++r) {
    const int rw = (r & 3) + 8 * (r >> 2) + 4 * h5;
    Os[(size_t)(i0 + rw) * 256 + jcol] = oa0[r] * inv;
    Os[(size_t)(i0 + 32 + rw) * 256 + jcol] = oa1[r] * inv;
    Os[(size_t)(i0 + 64 + rw) * 256 + jcol] = oa2[r] * inv;
    Os[(size_t)(i0 + 96 + rw) * 256 + jcol] = oa3[r] * inv;
  }
}

extern "C" void kernel_launch(void* const* d_in, const int* in_sizes, int n_in,
                              void* d_out, int out_size, void* d_ws,
                              size_t ws_size, hipStream_t stream) {
  const float* Q = (const float*)d_in[0];
  const float* K = (const float*)d_in[1];
  const float* V = (const float*)d_in[2];
  const float* di = (const float*)d_in[3];
  float* out = (float*)d_out;
  const int BC = in_sizes[0] / (256 * 256);  // 512 slices
  hipLaunchKernelGGL(attn_flash, dim3(BC * 2), dim3(512), 0, stream, Q, K, V,
                     di, out);
}

// Round 10
// 112.168 us; speedup vs baseline: 1.6575x; 1.2670x over previous
//
#include <hip/hip_runtime.h>
#include <hip/hip_bf16.h>

// Per (b,c) slice: S = (Q K^T)*di ; A = softmax_rows(S) ; out[i,j] = sum_k A[j,k] V[i,k]
// j-tile 128 (2 blocks/slice, XCD-paired), 8 waves, fp16 MFMA.
// Sized for 2 blocks/CU: LDS exactly 80KB, launch_bounds(512,4) caps regs at 128.
// mm1: 16 chunks of 16 K-rows (Kbuf 2x8KB dbuf), 16x16x32 f16, full-row softmax in regs.
// mm2: 8 chunks of V[64 i][128 k] (16KB, aliases Kbuf), wave tile 32i x 32j, 32x32x16.
// Raw s_barrier + lgkmcnt only; 2-deep register prefetch for K and V.

typedef __attribute__((ext_vector_type(8))) _Float16 f16x8;
typedef __attribute__((ext_vector_type(4))) float f32x4;
typedef __attribute__((ext_vector_type(16))) float f32x16;

#define BARRIER() asm volatile("s_waitcnt lgkmcnt(0)\n\ts_barrier" ::: "memory")

__device__ __forceinline__ f32x4 mfma16h(f16x8 a, f16x8 b, f32x4 c) {
  return __builtin_amdgcn_mfma_f32_16x16x32_f16(a, b, c, 0, 0, 0);
}
__device__ __forceinline__ f32x16 mfma32h(f16x8 a, f16x8 b, f32x16 c) {
  return __builtin_amdgcn_mfma_f32_32x32x16_f16(a, b, c, 0, 0, 0);
}
__device__ __forceinline__ f16x8 cvt8(f32x4 a, f32x4 b) {
  f16x8 r;
  r[0] = (_Float16)a[0]; r[1] = (_Float16)a[1];
  r[2] = (_Float16)a[2]; r[3] = (_Float16)a[3];
  r[4] = (_Float16)b[0]; r[5] = (_Float16)b[1];
  r[6] = (_Float16)b[2]; r[7] = (_Float16)b[3];
  return r;
}
// 512B-row-stride fp16 tiles ([*][256]): XOR 4 row bits into the 16B-slot idx
__device__ __forceinline__ int swzA(int row, int byteCol) {
  return row * 512 + (byteCol ^ ((row & 15) << 4));
}
// 256B-row-stride fp16 tile ([64][128]): same 4-bit XOR, 16 slots per row
__device__ __forceinline__ int swzV(int row, int byteCol) {
  return row * 256 + (byteCol ^ ((row & 15) << 4));
}

__global__ __launch_bounds__(512, 4) void attn_fused10(
    const float* __restrict__ Q, const float* __restrict__ K,
    const float* __restrict__ V, const float* __restrict__ di,
    float* __restrict__ out) {
  __shared__ short Kbuf[2][16 * 256];  // 2 x 8KB fp16 K chunks; alias: Vlds
  __shared__ short Abuf[128 * 256];    // 64KB fp16 attn weights, swizzled
  short* Vlds = &Kbuf[0][0];           // [64 i][128 k] fp16 = 16KB (alias)

  const int t = threadIdx.x;
  const int lane = t & 63;
  const int wv = t >> 6;     // 0..7
  const int l15 = lane & 15;
  const int l4 = (lane >> 4) & 3;
  const int l31 = lane & 31;
  const int h5 = lane >> 5;

  // 2 sibling blocks of one slice share bid%8 -> same XCD L2
  const int bid = blockIdx.x;
  const int bc = (bid >> 4) * 8 + (bid & 7);  // slice 0..511
  const int j0 = ((bid >> 3) & 1) << 7;       // 0 or 128

  const float dival = di[0];
  const size_t base = (size_t)bc << 16;
  const float* Qs = Q + base;
  const float* Ks = K + base;
  const float* Vs = V + base;
  float* Os = out + base;

  // K staging: thread loads 8 consecutive floats of a 16x256 chunk
  const int sr = t >> 5;         // row 0..15
  const int scb = (t & 31) << 4; // byteCol (fp16) = 16*(t&31)

  f32x4 kpA0, kpA1, kpB0, kpB1;  // 2-deep K prefetch
  {
    const float* p = Ks + sr * 256 + (t & 31) * 8;
    kpA0 = *(const f32x4*)p;
    kpA1 = *(const f32x4*)(p + 4);
    const float* q = p + 4096;  // next 16-row chunk
    kpB0 = *(const f32x4*)q;
    kpB1 = *(const f32x4*)(q + 4);
  }
  f16x8 qh[8];  // wave's 16 Q rows (A-op layout)
  {
    const float* qrow = Qs + (size_t)(j0 + 16 * wv + l15) * 256 + 8 * l4;
#pragma unroll
    for (int s = 0; s < 8; ++s)
      qh[s] = cvt8(*(const f32x4*)(qrow + 32 * s),
                   *(const f32x4*)(qrow + 32 * s + 4));
  }

  f32x4 acc[16];  // S rows j=16wv+4l4+r ; cols k = 16*idx + l15
#pragma unroll
  for (int i = 0; i < 16; ++i) acc[i] = (f32x4){0.f, 0.f, 0.f, 0.f};

  // ---- matmul 1: 16 chunks of 16 k-rows ----
#pragma unroll
  for (int ch = 0; ch < 16; ++ch) {
    short* kb = Kbuf[ch & 1];
    if ((ch & 1) == 0) {
      *(f16x8*)((char*)kb + swzA(sr, scb)) = cvt8(kpA0, kpA1);
      BARRIER();
      if (ch < 14) {
        const float* p = Ks + (ch + 2) * 4096 + sr * 256 + (t & 31) * 8;
        kpA0 = *(const f32x4*)p;
        kpA1 = *(const f32x4*)(p + 4);
      }
    } else {
      *(f16x8*)((char*)kb + swzA(sr, scb)) = cvt8(kpB0, kpB1);
      BARRIER();
      if (ch < 14) {
        const float* p = Ks + (ch + 2) * 4096 + sr * 256 + (t & 31) * 8;
        kpB0 = *(const f32x4*)p;
        kpB1 = *(const f32x4*)(p + 4);
      }
    }
    __builtin_amdgcn_s_setprio(1);
    f32x4 a = acc[ch];
#pragma unroll
    for (int s = 0; s < 8; ++s) {
      f16x8 bh = *(const f16x8*)((const char*)kb + swzA(l15, 64 * s + 16 * l4));
      a = mfma16h(qh[s], bh, a);
    }
    acc[ch] = a;
    __builtin_amdgcn_s_setprio(0);
  }

  // ---- V prefetch for mm2 chunks 0,1 (fly under softmax) ----
  const int vr = t >> 3;        // V-tile row 0..63
  const int vcf = (t & 7) * 16; // float col within 128-col half
  f32x4 vpA[4], vpB[4];
  {
    const float* p = Vs + (size_t)vr * 256 + vcf;  // ic=0, kh=0
#pragma unroll
    for (int e = 0; e < 4; ++e) vpA[e] = *(const f32x4*)(p + 4 * e);
    const float* q = p + 128;  // ic=0, kh=1
#pragma unroll
    for (int e = 0; e < 4; ++e) vpB[e] = *(const f32x4*)(q + 4 * e);
  }

  // ---- softmax: full k per wave, in-register (r6-verified) ----
  float mx[4] = {-1e30f, -1e30f, -1e30f, -1e30f};
#pragma unroll
  for (int idx = 0; idx < 16; ++idx)
#pragma unroll
    for (int r = 0; r < 4; ++r) {
      acc[idx][r] *= dival;
      mx[r] = fmaxf(mx[r], acc[idx][r]);
    }
#pragma unroll
  for (int o = 1; o <= 8; o <<= 1)
#pragma unroll
    for (int r = 0; r < 4; ++r) mx[r] = fmaxf(mx[r], __shfl_xor(mx[r], o));
  float sm[4] = {0.f, 0.f, 0.f, 0.f};
#pragma unroll
  for (int idx = 0; idx < 16; ++idx)
#pragma unroll
    for (int r = 0; r < 4; ++r) {
      acc[idx][r] = __expf(acc[idx][r] - mx[r]);
      sm[r] += acc[idx][r];
    }
#pragma unroll
  for (int o = 1; o <= 8; o <<= 1)
#pragma unroll
    for (int r = 0; r < 4; ++r) sm[r] += __shfl_xor(sm[r], o);
#pragma unroll
  for (int r = 0; r < 4; ++r) sm[r] = 1.0f / sm[r];
#pragma unroll
  for (int idx = 0; idx < 16; ++idx)
#pragma unroll
    for (int r = 0; r < 4; ++r) {
      const int row = 16 * wv + 4 * l4 + r;
      *(_Float16*)((char*)Abuf + swzA(row, 2 * (16 * idx + l15))) =
          (_Float16)(acc[idx][r] * sm[r]);
    }
  BARRIER();  // A visible; all mm1 Kbuf reads done (Vlds alias safe)

  // ---- matmul 2: 8 chunks = (4 i-chunks of 64) x (2 k-halves of 128) ----
  const int ig = wv >> 2;  // i 32-group within 64-row chunk
  const int jg = wv & 3;   // j 32-group within 128 j-tile
  f32x16 o = {};
#pragma unroll
  for (int cc = 0; cc < 8; ++cc) {
    const int kh = cc & 1;
    // stage V chunk (from 2-deep prefetch regs)
    if ((cc & 1) == 0) {
      *(f16x8*)((char*)Vlds + swzV(vr, 2 * vcf)) = cvt8(vpA[0], vpA[1]);
      *(f16x8*)((char*)Vlds + swzV(vr, 2 * vcf + 16)) = cvt8(vpA[2], vpA[3]);
      BARRIER();
      if (cc < 6) {
        const float* p =
            Vs + (size_t)(64 * ((cc + 2) >> 1) + vr) * 256 + vcf;  // kh=0
#pragma unroll
        for (int e = 0; e < 4; ++e) vpA[e] = *(const f32x4*)(p + 4 * e);
      }
    } else {
      *(f16x8*)((char*)Vlds + swzV(vr, 2 * vcf)) = cvt8(vpB[0], vpB[1]);
      *(f16x8*)((char*)Vlds + swzV(vr, 2 * vcf + 16)) = cvt8(vpB[2], vpB[3]);
      BARRIER();
      if (cc < 6) {
        const float* p =
            Vs + (size_t)(64 * ((cc + 2) >> 1) + vr) * 256 + 128 + vcf;
#pragma unroll
        for (int e = 0; e < 4; ++e) vpB[e] = *(const f32x4*)(p + 4 * e);
      }
    }
    __builtin_amdgcn_s_setprio(1);
#pragma unroll
    for (int kk = 0; kk < 8; ++kk) {
      f16x8 vfrag = *(const f16x8*)((const char*)Vlds +
                                    swzV(32 * ig + l31, 32 * kk + 16 * h5));
      f16x8 pfrag =
          *(const f16x8*)((const char*)Abuf +
                          swzA(32 * jg + l31, 256 * kh + 32 * kk + 16 * h5));
      o = mfma32h(vfrag, pfrag, o);
    }
    __builtin_amdgcn_s_setprio(0);
    if (kh == 1) {  // both k-halves accumulated: store this i-chunk
      const int rbase = 64 * (cc >> 1) + 32 * ig + 4 * h5;
      const int col = j0 + 32 * jg + l31;
#pragma unroll
      for (int reg = 0; reg < 16; ++reg) {
        const int rw = (reg & 3) + 8 * (reg >> 2);
        Os[(size_t)(rbase + rw) * 256 + col] = o[reg];
      }
      o = (f32x16){};
    }
    BARRIER();  // Vlds reads done before next chunk's write
  }
}

extern "C" void kernel_launch(void* const* d_in, const int* in_sizes, int n_in,
                              void* d_out, int out_size, void* d_ws,
                              size_t ws_size, hipStream_t stream) {
  const float* Q = (const float*)d_in[0];
  const float* K = (const float*)d_in[1];
  const float* V = (const float*)d_in[2];
  const float* di = (const float*)d_in[3];
  float* out = (float*)d_out;
  const int BC = in_sizes[0] / (256 * 256);  // 512 slices
  hipLaunchKernelGGL(attn_fused10, dim3(BC * 2), dim3(512), 0, stream, Q, K, V,
                     di, out);
}

// Round 12
// 106.781 us; speedup vs baseline: 1.7411x; 1.0505x over previous
//
#include <hip/hip_runtime.h>
#include <hip/hip_bf16.h>

// Per (b,c) slice: S = (Q K^T)*di ; A = softmax_rows(S) ; out[i,j] = sum_k A[j,k] V[i,k]
// ONE BLOCK PER SLICE: 1024 threads (16 waves), j-tile 256 -> K/V issued once.
// mm1: 16 chunks of 16 K-rows (Kbuf 2x8KB fp16 dbuf), 16x16x32 f16;
//      wave owns 16 j-rows; full-row softmax in registers (r10-verified).
// mm2: 8 phases = 4 i-chunks x 2 k-halves, V [64i][128k] fp16 (aliases Kbuf),
//      wave tile 32i x 32j via 32x32x16 (1KB LDS per 32k-FLOP MFMA).
// Raw s_barrier + lgkmcnt(0); 2-deep register prefetch for K and V.
// LDS 144KB -> 1 block/CU (16 waves = 4/SIMD); grid 512 = exactly 2 rounds.

typedef __attribute__((ext_vector_type(8))) _Float16 f16x8;
typedef __attribute__((ext_vector_type(4))) float f32x4;
typedef __attribute__((ext_vector_type(16))) float f32x16;

#define BARRIER() asm volatile("s_waitcnt lgkmcnt(0)\n\ts_barrier" ::: "memory")

__device__ __forceinline__ f32x4 mfma16h(f16x8 a, f16x8 b, f32x4 c) {
  return __builtin_amdgcn_mfma_f32_16x16x32_f16(a, b, c, 0, 0, 0);
}
__device__ __forceinline__ f32x16 mfma32h(f16x8 a, f16x8 b, f32x16 c) {
  return __builtin_amdgcn_mfma_f32_32x32x16_f16(a, b, c, 0, 0, 0);
}
__device__ __forceinline__ f16x8 cvt8(f32x4 a, f32x4 b) {
  f16x8 r;
  r[0] = (_Float16)a[0]; r[1] = (_Float16)a[1];
  r[2] = (_Float16)a[2]; r[3] = (_Float16)a[3];
  r[4] = (_Float16)b[0]; r[5] = (_Float16)b[1];
  r[6] = (_Float16)b[2]; r[7] = (_Float16)b[3];
  return r;
}
// 512B-row-stride fp16 tiles ([*][256]): XOR 4 row bits into the 16B-slot idx
__device__ __forceinline__ int swzA(int row, int byteCol) {
  return row * 512 + (byteCol ^ ((row & 15) << 4));
}
// 256B-row-stride fp16 tile ([64][128]): 4-bit XOR over 16 slots
__device__ __forceinline__ int swzV(int row, int byteCol) {
  return row * 256 + (byteCol ^ ((row & 15) << 4));
}

__global__ __launch_bounds__(1024, 4) void attn_fused11(
    const float* __restrict__ Q, const float* __restrict__ K,
    const float* __restrict__ V, const float* __restrict__ di,
    float* __restrict__ out) {
  __shared__ short Kbuf[2][16 * 256];  // 2 x 8KB fp16 K chunks; alias: Vlds
  __shared__ short Abuf[256 * 256];    // 128KB fp16 attn weights, swizzled
  short* Vlds = &Kbuf[0][0];           // [64 i][128 k] fp16 = 16KB (alias)

  const int t = threadIdx.x;
  const int lane = t & 63;
  const int wv = t >> 6;     // 0..15
  const int l15 = lane & 15;
  const int l4 = (lane >> 4) & 3;
  const int l31 = lane & 31;
  const int h5 = lane >> 5;

  const int bc = blockIdx.x;  // slice 0..511 (block owns whole slice)

  const float dival = di[0];
  const size_t base = (size_t)bc << 16;
  const float* Qs = Q + base;
  const float* Ks = K + base;
  const float* Vs = V + base;
  float* Os = out + base;

  // K staging: thread loads 4 consecutive floats of a 16x256 chunk,
  // writes 8 bytes (4 fp16). Both 8B halves of a 16B slot come from threads
  // with the same row -> same XOR -> swizzle-consistent.
  const int sr = t >> 6;          // row 0..15 (= wv)
  const int scf = (t & 63) << 2;  // float col

  f32x4 kpA, kpB;  // 2-deep K prefetch
  {
    const float* p = Ks + sr * 256 + scf;
    kpA = *(const f32x4*)p;
    kpB = *(const f32x4*)(p + 4096);  // next 16-row chunk
  }
  f16x8 qh[8];  // wave's 16 Q rows (A-op layout)
  {
    const float* qrow = Qs + (size_t)(16 * wv + l15) * 256 + 8 * l4;
#pragma unroll
    for (int s = 0; s < 8; ++s)
      qh[s] = cvt8(*(const f32x4*)(qrow + 32 * s),
                   *(const f32x4*)(qrow + 32 * s + 4));
  }

  f32x4 acc[16];  // S rows j=16wv+4l4+r ; cols k = 16*idx + l15
#pragma unroll
  for (int i = 0; i < 16; ++i) acc[i] = (f32x4){0.f, 0.f, 0.f, 0.f};

  // ---- matmul 1: 16 chunks of 16 k-rows ----
#pragma unroll
  for (int ch = 0; ch < 16; ++ch) {
    short* kb = Kbuf[ch & 1];
    {  // 8-byte store of 4 fp16
      _Float16 h4[4];
      f32x4 src = ((ch & 1) == 0) ? kpA : kpB;
      h4[0] = (_Float16)src[0];
      h4[1] = (_Float16)src[1];
      h4[2] = (_Float16)src[2];
      h4[3] = (_Float16)src[3];
      *(unsigned long long*)((char*)kb + swzA(sr, scf * 2)) =
          *(unsigned long long*)h4;
    }
    BARRIER();
    if (ch < 14) {
      const float* p = Ks + (ch + 2) * 4096 + sr * 256 + scf;
      if ((ch & 1) == 0)
        kpA = *(const f32x4*)p;
      else
        kpB = *(const f32x4*)p;
    }
    __builtin_amdgcn_s_setprio(1);
    f32x4 a = acc[ch];
#pragma unroll
    for (int s = 0; s < 8; ++s) {
      f16x8 bh = *(const f16x8*)((const char*)kb + swzA(l15, 64 * s + 16 * l4));
      a = mfma16h(qh[s], bh, a);
    }
    acc[ch] = a;
    __builtin_amdgcn_s_setprio(0);
  }

  // ---- V prefetch for mm2 phases 0,1 (fly under softmax) ----
  const int vr = t >> 4;         // V-tile row 0..63
  const int vcf = (t & 15) * 8;  // float col within 128-col half
  f32x4 vpA[2], vpB[2];
  {
    const float* p = Vs + (size_t)vr * 256 + vcf;  // ic=0, kh=0
    vpA[0] = *(const f32x4*)p;
    vpA[1] = *(const f32x4*)(p + 4);
    const float* q = p + 128;  // ic=0, kh=1
    vpB[0] = *(const f32x4*)q;
    vpB[1] = *(const f32x4*)(q + 4);
  }

  // ---- softmax: full k per wave, in-register (r10-verified) ----
  float mx[4] = {-1e30f, -1e30f, -1e30f, -1e30f};
#pragma unroll
  for (int idx = 0; idx < 16; ++idx)
#pragma unroll
    for (int r = 0; r < 4; ++r) {
      acc[idx][r] *= dival;
      mx[r] = fmaxf(mx[r], acc[idx][r]);
    }
#pragma unroll
  for (int o = 1; o <= 8; o <<= 1)
#pragma unroll
    for (int r = 0; r < 4; ++r) mx[r] = fmaxf(mx[r], __shfl_xor(mx[r], o));
  float sm[4] = {0.f, 0.f, 0.f, 0.f};
#pragma unroll
  for (int idx = 0; idx < 16; ++idx)
#pragma unroll
    for (int r = 0; r < 4; ++r) {
      acc[idx][r] = __expf(acc[idx][r] - mx[r]);
      sm[r] += acc[idx][r];
    }
#pragma unroll
  for (int o = 1; o <= 8; o <<= 1)
#pragma unroll
    for (int r = 0; r < 4; ++r) sm[r] += __shfl_xor(sm[r], o);
#pragma unroll
  for (int r = 0; r < 4; ++r) sm[r] = 1.0f / sm[r];
#pragma unroll
  for (int idx = 0; idx < 16; ++idx)
#pragma unroll
    for (int r = 0; r < 4; ++r) {
      const int row = 16 * wv + 4 * l4 + r;
      *(_Float16*)((char*)Abuf + swzA(row, 2 * (16 * idx + l15))) =
          (_Float16)(acc[idx][r] * sm[r]);
    }
  BARRIER();  // A visible; all mm1 Kbuf reads done (Vlds alias safe)

  // ---- matmul 2: 8 phases = 4 i-chunks(64) x 2 k-halves(128) ----
  const int ig = wv & 1;   // i 32-group within 64-row chunk
  const int jg = wv >> 1;  // j 32-group (0..7)
  f32x16 o = {};
#pragma unroll
  for (int cc = 0; cc < 8; ++cc) {
    const int kh = cc & 1;
    if ((cc & 1) == 0) {
      *(f16x8*)((char*)Vlds + swzV(vr, 2 * vcf)) = cvt8(vpA[0], vpA[1]);
      BARRIER();
      if (cc < 6) {
        const float* p = Vs + (size_t)(64 * ((cc + 2) >> 1) + vr) * 256 + vcf;
        vpA[0] = *(const f32x4*)p;
        vpA[1] = *(const f32x4*)(p + 4);
      }
    } else {
      *(f16x8*)((char*)Vlds + swzV(vr, 2 * vcf)) = cvt8(vpB[0], vpB[1]);
      BARRIER();
      if (cc < 6) {
        const float* p =
            Vs + (size_t)(64 * ((cc + 2) >> 1) + vr) * 256 + 128 + vcf;
        vpB[0] = *(const f32x4*)p;
        vpB[1] = *(const f32x4*)(p + 4);
      }
    }
    __builtin_amdgcn_s_setprio(1);
#pragma unroll
    for (int kk = 0; kk < 8; ++kk) {
      f16x8 vfrag = *(const f16x8*)((const char*)Vlds +
                                    swzV(32 * ig + l31, 32 * kk + 16 * h5));
      f16x8 pfrag =
          *(const f16x8*)((const char*)Abuf +
                          swzA(32 * jg + l31, 256 * kh + 32 * kk + 16 * h5));
      o = mfma32h(vfrag, pfrag, o);
    }
    __builtin_amdgcn_s_setprio(0);
    if (kh == 1) {  // both k-halves accumulated: store this i-chunk
      const int rbase = 64 * (cc >> 1) + 32 * ig + 4 * h5;
      const int col = 32 * jg + l31;
#pragma unroll
      for (int reg = 0; reg < 16; ++reg) {
        const int rw = (reg & 3) + 8 * (reg >> 2);
        Os[(size_t)(rbase + rw) * 256 + col] = o[reg];
      }
      o = (f32x16){};
    }
    BARRIER();  // Vlds reads done before next phase's write
  }
}

extern "C" void kernel_launch(void* const* d_in, const int* in_sizes, int n_in,
                              void* d_out, int out_size, void* d_ws,
                              size_t ws_size, hipStream_t stream) {
  const float* Q = (const float*)d_in[0];
  const float* K = (const float*)d_in[1];
  const float* V = (const float*)d_in[2];
  const float* di = (const float*)d_in[3];
  float* out = (float*)d_out;
  const int BC = in_sizes[0] / (256 * 256);  // 512 slices
  hipLaunchKernelGGL(attn_fused11, dim3(BC), dim3(1024), 0, stream, Q, K, V,
                     di, out);
}

// Round 13
// 105.549 us; speedup vs baseline: 1.7614x; 1.0117x over previous
//
#include <hip/hip_runtime.h>
#include <hip/hip_bf16.h>

// Per (b,c) slice: S = (Q K^T)*di ; A = softmax_rows(S) ; out[i,j] = sum_k A[j,k] V[i,k]
// ONE BLOCK PER SLICE: 1024 threads (16 waves), j-tile 256 -> K/V issued once.
// mm1: 8 chunks of 32 K-rows (Kbuf 2x16KB fp16 dbuf), 16x16x32 f16;
//      wave owns 16 j-rows; full-row softmax in registers (r12-verified).
// mm2: 8 phases = 4 i-chunks x 2 k-halves, V [64i][128k] fp16 DOUBLE-buffered
//      in the Kbuf area; wave tile 32i x 32j via 32x32x16.
// Raw s_barrier + lgkmcnt(0); 2-deep register prefetch for K and V.
// 18 barriers total (was 25). LDS 160KB exactly -> 1 block/CU (16 waves).

typedef __attribute__((ext_vector_type(8))) _Float16 f16x8;
typedef __attribute__((ext_vector_type(4))) float f32x4;
typedef __attribute__((ext_vector_type(16))) float f32x16;

#define BARRIER() asm volatile("s_waitcnt lgkmcnt(0)\n\ts_barrier" ::: "memory")

__device__ __forceinline__ f32x4 mfma16h(f16x8 a, f16x8 b, f32x4 c) {
  return __builtin_amdgcn_mfma_f32_16x16x32_f16(a, b, c, 0, 0, 0);
}
__device__ __forceinline__ f32x16 mfma32h(f16x8 a, f16x8 b, f32x16 c) {
  return __builtin_amdgcn_mfma_f32_32x32x16_f16(a, b, c, 0, 0, 0);
}
__device__ __forceinline__ f16x8 cvt8(f32x4 a, f32x4 b) {
  f16x8 r;
  r[0] = (_Float16)a[0]; r[1] = (_Float16)a[1];
  r[2] = (_Float16)a[2]; r[3] = (_Float16)a[3];
  r[4] = (_Float16)b[0]; r[5] = (_Float16)b[1];
  r[6] = (_Float16)b[2]; r[7] = (_Float16)b[3];
  return r;
}
// 512B-row-stride fp16 tiles ([*][256]): XOR 4 row bits into the 16B-slot idx
__device__ __forceinline__ int swzA(int row, int byteCol) {
  return row * 512 + (byteCol ^ ((row & 15) << 4));
}
// 256B-row-stride fp16 tile ([64][128]): 4-bit XOR over 16 slots
__device__ __forceinline__ int swzV(int row, int byteCol) {
  return row * 256 + (byteCol ^ ((row & 15) << 4));
}

__global__ __launch_bounds__(1024, 4) void attn_fused13(
    const float* __restrict__ Q, const float* __restrict__ K,
    const float* __restrict__ V, const float* __restrict__ di,
    float* __restrict__ out) {
  __shared__ short Kbuf[2][32 * 256];  // 2 x 16KB fp16 K chunks; alias: Vlds
  __shared__ short Abuf[256 * 256];    // 128KB fp16 attn weights, swizzled
  short* Vlds0 = &Kbuf[0][0];          // mm2 V dbuf half 0 (16KB)
  short* Vlds1 = &Kbuf[1][0];          // mm2 V dbuf half 1 (16KB)

  const int t = threadIdx.x;
  const int lane = t & 63;
  const int wv = t >> 6;     // 0..15
  const int l15 = lane & 15;
  const int l4 = (lane >> 4) & 3;
  const int l31 = lane & 31;
  const int h5 = lane >> 5;

  const int bc = blockIdx.x;  // slice 0..511 (block owns whole slice)

  const float dival = di[0];
  const size_t base = (size_t)bc << 16;
  const float* Qs = Q + base;
  const float* Ks = K + base;
  const float* Vs = V + base;
  float* Os = out + base;

  // K staging: thread loads 8 consecutive floats of a 32x256 chunk,
  // writes one swizzled 16B fp16 slot.
  const int sr = t >> 5;          // row 0..31
  const int scf = (t & 31) << 3;  // float col (8 per thread)

  f32x4 kpA0, kpA1, kpB0, kpB1;  // 2-deep K prefetch (chunks ch, ch+1)
  {
    const float* p = Ks + sr * 256 + scf;
    kpA0 = *(const f32x4*)p;
    kpA1 = *(const f32x4*)(p + 4);
    kpB0 = *(const f32x4*)(p + 8192);
    kpB1 = *(const f32x4*)(p + 8192 + 4);
  }
  f16x8 qh[8];  // wave's 16 Q rows (A-op layout)
  {
    const float* qrow = Qs + (size_t)(16 * wv + l15) * 256 + 8 * l4;
#pragma unroll
    for (int s = 0; s < 8; ++s)
      qh[s] = cvt8(*(const f32x4*)(qrow + 32 * s),
                   *(const f32x4*)(qrow + 32 * s + 4));
  }

  f32x4 acc[16];  // S rows j=16wv+4l4+r ; cols k = 16*idx + l15
#pragma unroll
  for (int i = 0; i < 16; ++i) acc[i] = (f32x4){0.f, 0.f, 0.f, 0.f};

  // ---- matmul 1: 8 chunks of 32 k-rows, single barrier per chunk ----
#pragma unroll
  for (int ch = 0; ch < 8; ++ch) {
    short* kb = Kbuf[ch & 1];
    if ((ch & 1) == 0) {
      *(f16x8*)((char*)kb + swzA(sr, scf * 2)) = cvt8(kpA0, kpA1);
    } else {
      *(f16x8*)((char*)kb + swzA(sr, scf * 2)) = cvt8(kpB0, kpB1);
    }
    BARRIER();
    if (ch < 6) {  // prefetch chunk ch+2 into the freed parity regs
      const float* p = Ks + (ch + 2) * 8192 + sr * 256 + scf;
      if ((ch & 1) == 0) {
        kpA0 = *(const f32x4*)p;
        kpA1 = *(const f32x4*)(p + 4);
      } else {
        kpB0 = *(const f32x4*)p;
        kpB1 = *(const f32x4*)(p + 4);
      }
    }
    __builtin_amdgcn_s_setprio(1);
#pragma unroll
    for (int kf = 0; kf < 2; ++kf) {
      const int kr = 16 * kf + l15;
      f32x4 a = acc[2 * ch + kf];
#pragma unroll
      for (int s = 0; s < 8; ++s) {
        f16x8 bh =
            *(const f16x8*)((const char*)kb + swzA(kr, 64 * s + 16 * l4));
        a = mfma16h(qh[s], bh, a);
      }
      acc[2 * ch + kf] = a;
    }
    __builtin_amdgcn_s_setprio(0);
  }

  // ---- V prefetch for mm2 phases 0,1 (fly under softmax) ----
  const int vr = t >> 4;         // V-tile row 0..63
  const int vcf = (t & 15) * 8;  // float col within 128-col half
  f32x4 vpA[2], vpB[2];
  {
    const float* p = Vs + (size_t)vr * 256 + vcf;  // ic=0, kh=0
    vpA[0] = *(const f32x4*)p;
    vpA[1] = *(const f32x4*)(p + 4);
    const float* q = p + 128;  // ic=0, kh=1
    vpB[0] = *(const f32x4*)q;
    vpB[1] = *(const f32x4*)(q + 4);
  }

  // ---- softmax: full k per wave, in-register (r12-verified) ----
  float mx[4] = {-1e30f, -1e30f, -1e30f, -1e30f};
#pragma unroll
  for (int idx = 0; idx < 16; ++idx)
#pragma unroll
    for (int r = 0; r < 4; ++r) {
      acc[idx][r] *= dival;
      mx[r] = fmaxf(mx[r], acc[idx][r]);
    }
#pragma unroll
  for (int o = 1; o <= 8; o <<= 1)
#pragma unroll
    for (int r = 0; r < 4; ++r) mx[r] = fmaxf(mx[r], __shfl_xor(mx[r], o));
  float sm[4] = {0.f, 0.f, 0.f, 0.f};
#pragma unroll
  for (int idx = 0; idx < 16; ++idx)
#pragma unroll
    for (int r = 0; r < 4; ++r) {
      acc[idx][r] = __expf(acc[idx][r] - mx[r]);
      sm[r] += acc[idx][r];
    }
#pragma unroll
  for (int o = 1; o <= 8; o <<= 1)
#pragma unroll
    for (int r = 0; r < 4; ++r) sm[r] += __shfl_xor(sm[r], o);
#pragma unroll
  for (int r = 0; r < 4; ++r) sm[r] = 1.0f / sm[r];
#pragma unroll
  for (int idx = 0; idx < 16; ++idx)
#pragma unroll
    for (int r = 0; r < 4; ++r) {
      const int row = 16 * wv + 4 * l4 + r;
      *(_Float16*)((char*)Abuf + swzA(row, 2 * (16 * idx + l15))) =
          (_Float16)(acc[idx][r] * sm[r]);
    }
  BARRIER();  // A visible; all mm1 Kbuf reads done (Vlds alias safe)

  // ---- matmul 2: 8 phases = 4 i-chunks(64) x 2 k-halves(128), V dbuf ----
  const int ig = wv & 1;   // i 32-group within 64-row chunk
  const int jg = wv >> 1;  // j 32-group (0..7)
  f32x16 o = {};
#pragma unroll
  for (int cc = 0; cc < 8; ++cc) {
    const int kh = cc & 1;
    short* vb = (cc & 1) ? Vlds1 : Vlds0;  // dbuf by parity
    if ((cc & 1) == 0) {
      *(f16x8*)((char*)vb + swzV(vr, 2 * vcf)) = cvt8(vpA[0], vpA[1]);
    } else {
      *(f16x8*)((char*)vb + swzV(vr, 2 * vcf)) = cvt8(vpB[0], vpB[1]);
    }
    BARRIER();  // single barrier per phase (dbuf)
    if (cc < 6) {  // prefetch phase cc+2 into freed parity regs
      const float* p = Vs + (size_t)(64 * ((cc + 2) >> 1) + vr) * 256 +
                       ((cc & 1) ? 128 : 0) + vcf;
      if ((cc & 1) == 0) {
        vpA[0] = *(const f32x4*)p;
        vpA[1] = *(const f32x4*)(p + 4);
      } else {
        vpB[0] = *(const f32x4*)p;
        vpB[1] = *(const f32x4*)(p + 4);
      }
    }
    __builtin_amdgcn_s_setprio(1);
#pragma unroll
    for (int kk = 0; kk < 8; ++kk) {
      f16x8 vfrag = *(const f16x8*)((const char*)vb +
                                    swzV(32 * ig + l31, 32 * kk + 16 * h5));
      f16x8 pfrag =
          *(const f16x8*)((const char*)Abuf +
                          swzA(32 * jg + l31, 256 * kh + 32 * kk + 16 * h5));
      o = mfma32h(vfrag, pfrag, o);
    }
    __builtin_amdgcn_s_setprio(0);
    if (kh == 1) {  // both k-halves accumulated: store this i-chunk
      const int rbase = 64 * (cc >> 1) + 32 * ig + 4 * h5;
      const int col = 32 * jg + l31;
#pragma unroll
      for (int reg = 0; reg < 16; ++reg) {
        const int rw = (reg & 3) + 8 * (reg >> 2);
        Os[(size_t)(rbase + rw) * 256 + col] = o[reg];
      }
      o = (f32x16){};
    }
  }
}

extern "C" void kernel_launch(void* const* d_in, const int* in_sizes, int n_in,
                              void* d_out, int out_size, void* d_ws,
                              size_t ws_size, hipStream_t stream) {
  const float* Q = (const float*)d_in[0];
  const float* K = (const float*)d_in[1];
  const float* V = (const float*)d_in[2];
  const float* di = (const float*)d_in[3];
  float* out = (float*)d_out;
  const int BC = in_sizes[0] / (256 * 256);  // 512 slices
  hipLaunchKernelGGL(attn_fused13, dim3(BC), dim3(1024), 0, stream, Q, K, V,
                     di, out);
}